// Round 1
// 1133.476 us; speedup vs baseline: 1.1212x; 1.1212x over previous
//
#include <hip/hip_runtime.h>
#include <stdint.h>

// HistMatching via stable LSD radix sort (4 x 8-bit passes) of (key32,idx32)
// u64 pairs per segment. Stability via per-(bin,block) histogram matrix +
// exclusive scan (no per-element global atomics). Final pass fuses the
// epilogue: template -> tsorted[dest]=val; samples -> out[idx]=tsorted[dest].
//
// R1: part_k rewritten for occupancy. (a) single LDS tile buffer — the 2-bit
// split rounds read all elements into registers before the first barrier in
// scan_pack2 and scatter after it, so in-place is race-free; LDS 73K->37K ->
// 4 blocks/CU instead of 2. (b) per-digit local starts via sorted-run boundary
// detection instead of LDS-atomic hist + scan (kills hot-bin atomic
// serialization, esp. pass 3 top-byte). (c) Hbk base gather hoisted to kernel
// entry so its latency hides under the sort rounds.

#define SEG_N 2621440            // 128*160*128
#define NSEG 9                   // template + 8 samples
#define TILE 4096
#define NBLK (SEG_N / TILE)      // 640 blocks per segment
#define RADIX 256
#define HL (RADIX * NBLK)        // 163840 histogram-matrix entries per seg
#define SCHUNK 4096
#define SNB (HL / SCHUNK)        // 40 scan blocks per seg
#define SBUF (TILE + (TILE >> 4))  // 4352 u64, padded 1-per-16

// monotone f32 -> u32 (order-preserving)
__device__ __forceinline__ uint32_t fkey(float f) {
  uint32_t b = __float_as_uint(f);
  return b ^ ((b & 0x80000000u) ? 0xFFFFFFFFu : 0x80000000u);
}
__device__ __forceinline__ float finv(uint32_t u) {
  uint32_t b = u ^ ((u & 0x80000000u) ? 0x80000000u : 0xFFFFFFFFu);
  return __uint_as_float(b);
}
__device__ __forceinline__ uint32_t SIDX(uint32_t i) { return i + (i >> 4); }

// ---------- init: build pairsA in index order + digit-0 histogram ----------
__global__ __launch_bounds__(256) void init_k(const float* __restrict__ x,
                                              const float* __restrict__ tmpl,
                                              int segbase,
                                              uint64_t* __restrict__ pairsA,
                                              uint32_t* __restrict__ Hkb) {
  __shared__ uint32_t hist[RADIX];
  const int t = threadIdx.x;
  const int blk = blockIdx.x;
  const int sl = blockIdx.y;
  const int seg = segbase + sl;
  const float* src = (seg == 0) ? tmpl : (x + (size_t)(seg - 1) * SEG_N);
  uint64_t* pa = pairsA + (size_t)sl * SEG_N;
  hist[t] = 0;
  __syncthreads();
  const uint32_t base = blk * TILE;
  const float4* s4 = reinterpret_cast<const float4*>(src + base);
#pragma unroll
  for (int r = 0; r < 4; ++r) {
    float4 v = s4[r * 256 + t];
    uint32_t i0 = base + (uint32_t)(r * 256 + t) * 4u;
    float f[4] = {v.x, v.y, v.z, v.w};
#pragma unroll
    for (int c = 0; c < 4; ++c) {
      uint32_t k = fkey(f[c]);
      atomicAdd(&hist[k & 255u], 1u);
      pa[i0 + c] = ((uint64_t)k << 32) | (uint64_t)(i0 + c);
    }
  }
  __syncthreads();
  Hkb[(size_t)sl * HL + (size_t)blk * RADIX + t] = hist[t];  // [blk][bin]
}

// ---------- histogram of digit p over current pairs ----------
__global__ __launch_bounds__(256) void hist_k(const uint64_t* __restrict__ pairs,
                                              uint32_t* __restrict__ Hkb, int p) {
  __shared__ uint32_t hist[RADIX];
  const int t = threadIdx.x;
  const int blk = blockIdx.x;
  const int sl = blockIdx.y;
  const uint64_t* pc = pairs + (size_t)sl * SEG_N + (size_t)blk * TILE;
  hist[t] = 0;
  __syncthreads();
  const int sh = 32 + 8 * p;
#pragma unroll
  for (int r = 0; r < 16; ++r) {
    uint64_t e = pc[r * 256 + t];
    atomicAdd(&hist[(uint32_t)(e >> sh) & 255u], 1u);
  }
  __syncthreads();
  Hkb[(size_t)sl * HL + (size_t)blk * RADIX + t] = hist[t];
}

// ---------- transpose [blk][bin] -> [bin][blk] (scan-order) ----------
__global__ __launch_bounds__(256) void transp_k(const uint32_t* __restrict__ Hkb,
                                                uint32_t* __restrict__ Hbk) {
  __shared__ uint32_t tile[64][65];
  const int sl = blockIdx.y;
  const uint32_t* src = Hkb + (size_t)sl * HL;
  uint32_t* dst = Hbk + (size_t)sl * HL;
  const int kt = blockIdx.x % (NBLK / 64);  // 10 k-tiles
  const int bt = blockIdx.x / (NBLK / 64);  // 4 b-tiles
  const int tx = threadIdx.x & 63, ty = threadIdx.x >> 6;
#pragma unroll
  for (int r = 0; r < 16; ++r) {
    int k = kt * 64 + ty + r * 4;
    tile[ty + r * 4][tx] = src[(size_t)k * RADIX + bt * 64 + tx];
  }
  __syncthreads();
#pragma unroll
  for (int r = 0; r < 16; ++r) {
    int b = bt * 64 + ty + r * 4;
    dst[(size_t)b * NBLK + kt * 64 + tx] = tile[tx][ty + r * 4];
  }
}

// ---------- 3-level exclusive scan over Hbk (length HL per seg) ----------
__device__ __forceinline__ uint32_t block_excl_scan_256(uint32_t v, uint32_t* lds) {
  const int t = threadIdx.x;
  lds[t] = v;
  __syncthreads();
#pragma unroll
  for (int off = 1; off < 256; off <<= 1) {
    uint32_t a = (t >= off) ? lds[t - off] : 0u;
    __syncthreads();
    lds[t] += a;
    __syncthreads();
  }
  uint32_t ex = (t == 0) ? 0u : lds[t - 1];
  __syncthreads();
  return ex;
}

__global__ __launch_bounds__(256) void scan_a_k(const uint32_t* __restrict__ Hbk,
                                                uint32_t* __restrict__ partials) {
  __shared__ uint32_t lds[256];
  const int t = threadIdx.x;
  const uint32_t* c = Hbk + (size_t)blockIdx.y * HL +
                      (size_t)blockIdx.x * SCHUNK + (size_t)t * 16;
  const uint4* p = reinterpret_cast<const uint4*>(c);
  uint32_t s = 0;
#pragma unroll
  for (int k = 0; k < 4; ++k) { uint4 a = p[k]; s += a.x + a.y + a.z + a.w; }
  lds[t] = s;
  __syncthreads();
  for (int off = 128; off > 0; off >>= 1) {
    if (t < off) lds[t] += lds[t + off];
    __syncthreads();
  }
  if (t == 0) partials[blockIdx.y * 64 + blockIdx.x] = lds[0];
}

__global__ __launch_bounds__(256) void scan_b_k(uint32_t* __restrict__ partials) {
  __shared__ uint32_t lds[256];
  const int t = threadIdx.x;
  uint32_t* p = partials + blockIdx.y * 64;
  uint32_t v = (t < SNB) ? p[t] : 0u;
  uint32_t ex = block_excl_scan_256(v, lds);
  if (t < SNB) p[t] = ex;
}

__global__ __launch_bounds__(256) void scan_c_k(uint32_t* __restrict__ Hbk,
                                                const uint32_t* __restrict__ partials) {
  __shared__ uint32_t lds[256];
  const int t = threadIdx.x;
  uint32_t* c = Hbk + (size_t)blockIdx.y * HL +
                (size_t)blockIdx.x * SCHUNK + (size_t)t * 16;
  uint4* p = reinterpret_cast<uint4*>(c);
  uint4 a[4];
  uint32_t s = 0;
#pragma unroll
  for (int k = 0; k < 4; ++k) {
    a[k] = p[k];
    s += a[k].x + a[k].y + a[k].z + a[k].w;
  }
  uint32_t ex = block_excl_scan_256(s, lds);
  uint32_t run = partials[blockIdx.y * 64 + blockIdx.x] + ex;
#pragma unroll
  for (int k = 0; k < 4; ++k) {
    uint4 o;
    o.x = run; run += a[k].x;
    o.y = run; run += a[k].y;
    o.z = run; run += a[k].z;
    o.w = run; run += a[k].w;
    p[k] = o;
  }
}

// ---------- dual packed-u16 exclusive scan over 256 threads ----------
__device__ __forceinline__ void scan_pack2(uint32_t v0, uint32_t v1, uint32_t* s,
                                           uint32_t& ex0, uint32_t& ex1,
                                           uint32_t& tot0, uint32_t& tot1) {
  const int lane = threadIdx.x & 63, w = threadIdx.x >> 6;
  uint32_t a = v0, b = v1;
#pragma unroll
  for (int o = 1; o < 64; o <<= 1) {
    uint32_t na = __shfl_up(a, (unsigned)o, 64);
    uint32_t nb = __shfl_up(b, (unsigned)o, 64);
    if (lane >= o) { a += na; b += nb; }
  }
  if (lane == 63) { s[w] = a; s[4 + w] = b; }
  __syncthreads();   // NOTE: also the read/write fence for the in-place split
  if (threadIdx.x == 0) {
    uint32_t r0 = 0, r1 = 0;
#pragma unroll
    for (int i = 0; i < 4; ++i) {
      uint32_t q0 = s[i], q1 = s[4 + i];
      s[i] = r0; s[4 + i] = r1;
      r0 += q0; r1 += q1;
    }
    s[8] = r0; s[9] = r1;
  }
  __syncthreads();
  ex0 = a - v0 + s[w];
  ex1 = b - v1 + s[4 + w];
  tot0 = s[8]; tot1 = s[9];
  __syncthreads();  // protect scratch before next-round reuse
}

// ---------- stable partition pass (templated digit P, output MODE) ----------
// MODE 0: write pairs to dst; MODE 1: tsorted[dest]=val; MODE 2: out[idx]=tsorted[dest]
template <int P, int MODE>
__global__ __launch_bounds__(256) void part_k(const uint64_t* __restrict__ src,
                                              uint64_t* __restrict__ dst,
                                              const uint32_t* __restrict__ Hbk,
                                              float* __restrict__ tsorted,
                                              float* __restrict__ out,
                                              int segbase, int slbase) {
  __shared__ uint64_t buf[SBUF];       // single tile buffer (in-place split)
  __shared__ uint32_t ldsStart[RADIX];
  __shared__ uint32_t ldsBase[RADIX];
  __shared__ uint32_t scanS[12];
  const int t = threadIdx.x;
  const int blk = blockIdx.x;
  const int sl = slbase + blockIdx.y;
  const int seg = segbase + sl;
  const uint64_t* ps = src + (size_t)sl * SEG_N + (size_t)blk * TILE;

  // hoisted: per-digit global base (uncoalesced gather; latency hides under
  // the sort rounds — first consumer is the emit loop at the end)
  ldsBase[t] = Hbk[(size_t)sl * HL + (size_t)t * NBLK + blk];

  // stage tile into LDS (coalesced), padded layout
#pragma unroll
  for (int r = 0; r < 16; ++r) buf[SIDX(r * 256 + t)] = ps[r * 256 + t];
  __syncthreads();

  // 4 stable 2-bit split rounds (LSB-first within the byte), IN PLACE:
  // every thread reads its 16 elements into registers BEFORE the first
  // barrier inside scan_pack2; all scatter writes happen AFTER it.
  uint64_t e[16];
#pragma unroll
  for (int rnd = 0; rnd < 4; ++rnd) {
#pragma unroll
    for (int j = 0; j < 16; ++j) e[j] = buf[SIDX(t * 16 + j)];
    uint32_t cnt[4] = {0u, 0u, 0u, 0u};
#pragma unroll
    for (int j = 0; j < 16; ++j) {
      uint32_t d2 = (uint32_t)(e[j] >> (32 + 8 * P + 2 * rnd)) & 3u;
      cnt[d2]++;
    }
    uint32_t p0 = cnt[0] | (cnt[1] << 16);
    uint32_t p1 = cnt[2] | (cnt[3] << 16);
    uint32_t ex0, ex1, tot0, tot1;
    scan_pack2(p0, p1, scanS, ex0, ex1, tot0, tot1);
    uint32_t t0 = tot0 & 0xffffu, t1 = tot0 >> 16, t2 = tot1 & 0xffffu;
    uint32_t pos[4];
    pos[0] = (ex0 & 0xffffu);
    pos[1] = t0 + (ex0 >> 16);
    pos[2] = t0 + t1 + (ex1 & 0xffffu);
    pos[3] = t0 + t1 + t2 + (ex1 >> 16);
#pragma unroll
    for (int j = 0; j < 16; ++j) {
      uint32_t d2 = (uint32_t)(e[j] >> (32 + 8 * P + 2 * rnd)) & 3u;
      buf[SIDX(pos[d2]++)] = e[j];
    }
    __syncthreads();
  }
  // buf: tile stably sorted by digit P

  // per-digit local starts via sorted-run boundary detection (replaces the
  // LDS-atomic histogram + scan: start-of-run == exclusive prefix of counts).
  // Only digits present in the tile get a start — those are the only ones read.
  const uint8_t* b8 = reinterpret_cast<const uint8_t*>(buf);
#pragma unroll
  for (int r = 0; r < 16; ++r) {
    uint32_t s = (uint32_t)(r * 256 + t);
    e[r] = buf[SIDX(s)];
    uint32_t d = (uint32_t)(e[r] >> (32 + 8 * P)) & 255u;
    uint32_t dp = (s == 0) ? 0x100u
                           : (uint32_t)b8[(size_t)SIDX(s - 1) * 8 + 4 + P];
    if (d != dp) ldsStart[d] = s;
  }
  __syncthreads();

  // emit in sorted-tile order: digit runs -> contiguous global ranges
#pragma unroll
  for (int r = 0; r < 16; ++r) {
    uint32_t s = (uint32_t)(r * 256 + t);
    uint64_t el = e[r];
    uint32_t d = (uint32_t)(el >> (32 + 8 * P)) & 255u;
    uint32_t dest = ldsBase[d] + s - ldsStart[d];
    if (MODE == 0) {
      dst[(size_t)sl * SEG_N + dest] = el;
    } else if (MODE == 1) {
      tsorted[dest] = finv((uint32_t)(el >> 32));
    } else {
      out[(size_t)(seg - 1) * SEG_N + (uint32_t)el] = tsorted[dest];
    }
  }
}

// ---------------------------------------------------------------------------
extern "C" void kernel_launch(void* const* d_in, const int* in_sizes, int n_in,
                              void* d_out, int out_size, void* d_ws, size_t ws_size,
                              hipStream_t stream) {
  const float* x = (const float*)d_in[0];
  const float* tmpl = (const float*)d_in[1];
  float* out = (float*)d_out;

  auto need = [](int nb) -> size_t {
    return (size_t)nb * ((size_t)SEG_N * 16 + (size_t)HL * 8 + 256) +
           (size_t)SEG_N * 4 + 8192;
  };
  const int nb = (ws_size >= need(9)) ? 9 : (ws_size >= need(3)) ? 3 : 1;

  uint8_t* w = (uint8_t*)d_ws;
  size_t off = 0;
  auto carve = [&](size_t bytes) -> void* {
    void* p = w + off;
    off = (off + bytes + 255) & ~(size_t)255;
    return p;
  };
  uint64_t* pairsA = (uint64_t*)carve((size_t)nb * SEG_N * 8);
  uint64_t* pairsB = (uint64_t*)carve((size_t)nb * SEG_N * 8);
  uint32_t* Hkb = (uint32_t*)carve((size_t)nb * HL * 4);
  uint32_t* Hbk = (uint32_t*)carve((size_t)nb * HL * 4);
  uint32_t* partials = (uint32_t*)carve((size_t)nb * 64 * 4);
  float* tsorted = (float*)carve((size_t)SEG_N * 4);

  for (int g = 0; g < NSEG; g += nb) {
    const dim3 gi(NBLK, nb);
    const dim3 gt(40, nb);
    const dim3 gs(SNB, nb);
    const dim3 g1(1, nb);

    auto scan_h = [&]() {
      transp_k<<<gt, 256, 0, stream>>>(Hkb, Hbk);
      scan_a_k<<<gs, 256, 0, stream>>>(Hbk, partials);
      scan_b_k<<<g1, 256, 0, stream>>>(partials);
      scan_c_k<<<gs, 256, 0, stream>>>(Hbk, partials);
    };

    // pass 0 (digit-0 hist fused into init)
    init_k<<<gi, 256, 0, stream>>>(x, tmpl, g, pairsA, Hkb);
    scan_h();
    part_k<0, 0><<<gi, 256, 0, stream>>>(pairsA, pairsB, Hbk, tsorted, out, g, 0);
    // pass 1
    hist_k<<<gi, 256, 0, stream>>>(pairsB, Hkb, 1);
    scan_h();
    part_k<1, 0><<<gi, 256, 0, stream>>>(pairsB, pairsA, Hbk, tsorted, out, g, 0);
    // pass 2
    hist_k<<<gi, 256, 0, stream>>>(pairsA, Hkb, 2);
    scan_h();
    part_k<2, 0><<<gi, 256, 0, stream>>>(pairsA, pairsB, Hbk, tsorted, out, g, 0);
    // pass 3 (fused epilogue)
    hist_k<<<gi, 256, 0, stream>>>(pairsB, Hkb, 3);
    scan_h();
    if (g == 0) {
      part_k<3, 1><<<dim3(NBLK, 1), 256, 0, stream>>>(pairsB, pairsA, Hbk,
                                                      tsorted, out, g, 0);
      if (nb > 1)
        part_k<3, 2><<<dim3(NBLK, nb - 1), 256, 0, stream>>>(pairsB, pairsA, Hbk,
                                                             tsorted, out, g, 1);
    } else {
      part_k<3, 2><<<dim3(NBLK, nb), 256, 0, stream>>>(pairsB, pairsA, Hbk,
                                                       tsorted, out, g, 0);
    }
  }
}